// Round 20
// baseline (749.434 us; speedup 1.0000x reference)
//
#include <hip/hip_runtime.h>
#include <math.h>

// BracketNet producer/consumer: one workgroup (2 waves) per (b,h) chain.
//   wave 1 (producer): z[s] = b + Wx·x[s] -> 64-entry LDS ring (~200 cyc/step,
//           steps independent, self-paced; vmcnt(7) pipelined x loads).
//   wave 0 (consumer): ctx_{s+1} = GELU(Wc·ctx_s + z_s); out = x + ctx.
//           r16 engine (478 cyc/step, best measured): pack g (DPP+pkrtz),
//           32 readlanes + one fence, 32 v_dot2_f32_f16, 3-term erf gelu,
//           depth-8 counted-vmcnt volatile-asm x pipeline. z arrives via
//           LDS ring, batch-prefetched one batch ahead (off critical path).
// Sync: two LDS flags, spin + s_sleep, NO barriers (a barrier would drain
// vmcnt and expose store-ack/HBM latency — r1 lesson). Ring protocol:
// producer ahead <= 8 batches (ring cap), consumer requires >= 2 ahead;
// release lags reads by one batch -> no overwrite of in-flight reads.
//
// r15/r19 law (measured twice): one wave's stall cycles can't be filled by
// its own independent work (marginal issue ~additive). Fill them from
// ANOTHER wave -> producer/consumer specialization.

typedef float    f32x4 __attribute__((ext_vector_type(4)));
typedef _Float16 f16x2 __attribute__((ext_vector_type(2)));

#define S_LEN 2048
#define B_SZ  64
#define D_SZ  512
#define DIM   64
#define STRIDE ((size_t)(B_SZ * D_SZ))   // floats between consecutive s

__device__ __forceinline__ int pkrtz(float a, float b) {
    return __builtin_bit_cast(int, __builtin_amdgcn_cvt_pkrtz(a, b));
}

__device__ __forceinline__ float fdot2h(int pack, int wpk, float acc) {
#if __has_builtin(__builtin_amdgcn_fdot2)
    return __builtin_amdgcn_fdot2(__builtin_bit_cast(f16x2, pack),
                                  __builtin_bit_cast(f16x2, wpk), acc, false);
#else
    float d;
    asm("v_dot2_f32_f16 %0, %1, %2, %3"
        : "=v"(d)
        : "v"(__builtin_bit_cast(f16x2, pack)),
          "v"(__builtin_bit_cast(f16x2, wpk)), "v"(acc));
    return d;
#endif
}

// 3-term A&S 7.1.25 erf gelu (|eps|<=2.5e-5), fma-combined tail.
__device__ __forceinline__ float gelu_fast(float y) {
    const float ax = fabsf(y) * 0.70710678118654752440f;
    const float t  = __builtin_amdgcn_rcpf(fmaf(0.47047f, ax, 1.0f));
    const float e  = __builtin_amdgcn_exp2f(-ax * ax * 1.44269504088896f);
    float p = fmaf(0.7478556f, t, -0.0958798f);
    p = fmaf(p, t, 0.3480242f);
    p *= t;
    float er = fmaf(-p, e, 1.0f);
    er = copysignf(er, y);
    const float m = 0.5f * y;
    return fmaf(m, er, m);
}

#define GLOAD(dst, ptr) \
    asm volatile("global_load_dword %0, %1, off" : "=v"(dst) : "v"(ptr))
#define GSTORE(val, ptr) \
    asm volatile("global_store_dword %1, %0, off" : : "v"(val), "v"(ptr) : "memory")

#define RLN(s, l) __builtin_amdgcn_readlane(s, l)

#define RLA32(t, s)                                                           \
    t[0]  = RLN(s, 0);  t[1]  = RLN(s, 2);  t[2]  = RLN(s, 4);                \
    t[3]  = RLN(s, 6);  t[4]  = RLN(s, 8);  t[5]  = RLN(s, 10);               \
    t[6]  = RLN(s, 12); t[7]  = RLN(s, 14); t[8]  = RLN(s, 16);               \
    t[9]  = RLN(s, 18); t[10] = RLN(s, 20); t[11] = RLN(s, 22);               \
    t[12] = RLN(s, 24); t[13] = RLN(s, 26); t[14] = RLN(s, 28);               \
    t[15] = RLN(s, 30); t[16] = RLN(s, 32); t[17] = RLN(s, 34);               \
    t[18] = RLN(s, 36); t[19] = RLN(s, 38); t[20] = RLN(s, 40);               \
    t[21] = RLN(s, 42); t[22] = RLN(s, 44); t[23] = RLN(s, 46);               \
    t[24] = RLN(s, 48); t[25] = RLN(s, 50); t[26] = RLN(s, 52);               \
    t[27] = RLN(s, 54); t[28] = RLN(s, 56); t[29] = RLN(s, 58);               \
    t[30] = RLN(s, 60); t[31] = RLN(s, 62)

#define DOTS32(P, t, wa)                                                      \
    P##0 = fdot2h(t[0],  wa[0],  P##0); P##1 = fdot2h(t[1],  wa[1],  P##1);   \
    P##2 = fdot2h(t[2],  wa[2],  P##2); P##3 = fdot2h(t[3],  wa[3],  P##3);   \
    P##4 = fdot2h(t[4],  wa[4],  P##4); P##5 = fdot2h(t[5],  wa[5],  P##5);   \
    P##6 = fdot2h(t[6],  wa[6],  P##6); P##7 = fdot2h(t[7],  wa[7],  P##7);   \
    P##0 = fdot2h(t[8],  wa[8],  P##0); P##1 = fdot2h(t[9],  wa[9],  P##1);   \
    P##2 = fdot2h(t[10], wa[10], P##2); P##3 = fdot2h(t[11], wa[11], P##3);   \
    P##4 = fdot2h(t[12], wa[12], P##4); P##5 = fdot2h(t[13], wa[13], P##5);   \
    P##6 = fdot2h(t[14], wa[14], P##6); P##7 = fdot2h(t[15], wa[15], P##7);   \
    P##0 = fdot2h(t[16], wa[16], P##0); P##1 = fdot2h(t[17], wa[17], P##1);   \
    P##2 = fdot2h(t[18], wa[18], P##2); P##3 = fdot2h(t[19], wa[19], P##3);   \
    P##4 = fdot2h(t[20], wa[20], P##4); P##5 = fdot2h(t[21], wa[21], P##5);   \
    P##6 = fdot2h(t[22], wa[22], P##6); P##7 = fdot2h(t[23], wa[23], P##7);   \
    P##0 = fdot2h(t[24], wa[24], P##0); P##1 = fdot2h(t[25], wa[25], P##1);   \
    P##2 = fdot2h(t[26], wa[26], P##2); P##3 = fdot2h(t[27], wa[27], P##3);   \
    P##4 = fdot2h(t[28], wa[28], P##4); P##5 = fdot2h(t[29], wa[29], P##5);   \
    P##6 = fdot2h(t[30], wa[30], P##6); P##7 = fdot2h(t[31], wa[31], P##7)

#define RED8(P) (((P##0 + P##1) + (P##2 + P##3)) + ((P##4 + P##5) + (P##6 + P##7)))

#define PACK_PAIR(dst, val)                                                   \
    const int dst##_i = __float_as_int(val);                                  \
    const int dst##_s = __builtin_amdgcn_mov_dpp(dst##_i, 0x101, 0xf, 0xf, true); \
    const int dst = pkrtz(val, __int_as_float(dst##_s))

#define SPIN_GE(ptr, val)                                                     \
    do {                                                                      \
        for (;;) {                                                            \
            const int v_ = *(ptr);                                            \
            if (v_ >= (val)) break;                                            \
            asm volatile("s_sleep 2");                                        \
        }                                                                     \
        asm volatile("" ::: "memory");                                        \
    } while (0)

__global__ __launch_bounds__(128, 1) void bracket_pc(
    const float* __restrict__ src, const float* __restrict__ W,
    const float* __restrict__ bias, float* __restrict__ out)
{
    const int tid  = threadIdx.x;
    const int wid  = tid >> 6;
    const int lane = tid & 63;
    const int bb   = blockIdx.x >> 3;
    const int hh   = blockIdx.x & 7;

    __shared__ float zring[64][DIM];     // 16 KB: 8 batches x 8 steps
    __shared__ int prodflag;             // z[0..p-1] written
    __shared__ int consflag;             // batches < c/8 fully consumed

    if (tid == 0) { prodflag = 0; consflag = 0; }
    __syncthreads();                     // once, at start — no barriers after

    volatile int* pfv = &prodflag;
    volatile int* cfv = &consflag;

    const float* sp = src + (size_t)bb * D_SZ + hh * DIM + lane;

    if (wid == 1) {
        // ================= PRODUCER: z[s] = b + Wx·x[s] =================
        f32x4 w[16];
        {
            const float* wb = W + (size_t)(hh * DIM + lane) * (2 * DIM) + DIM;
#pragma unroll
            for (int i = 0; i < 16; ++i)
                asm volatile("global_load_dwordx4 %0, %1, off offset:%2"
                             : "=v"(w[i]) : "v"(wb), "i"(16 * i));
        }
        asm volatile("s_waitcnt vmcnt(0)" ::: "memory");
        __builtin_amdgcn_sched_barrier(0);
        int wpx[32];
#pragma unroll
        for (int j = 0; j < 16; ++j) {
            wpx[2 * j]     = pkrtz(w[j].x, w[j].y);
            wpx[2 * j + 1] = pkrtz(w[j].z, w[j].w);
        }
        const float bv = bias[hh * DIM + lane];

        const float* ppx    = sp;
        const float* plastx = sp + (size_t)(S_LEN - 1) * STRIDE;
        float xq[8];
#pragma unroll
        for (int i = 0; i < 8; ++i) { GLOAD(xq[i], ppx); ppx += STRIDE; }

        for (int j = 0; j < 256; ++j) {
            if (j >= 8) SPIN_GE(cfv, 8 * j - 56);   // ring space (<=8 ahead)
            const int sbase = (8 * j) & 63;
#pragma unroll
            for (int i = 0; i < 8; ++i) {
                asm volatile("s_waitcnt vmcnt(7)");
                __builtin_amdgcn_sched_barrier(0);
                PACK_PAIR(xp_, xq[i]);
                int tz[32];
                RLA32(tz, xp_);
                __builtin_amdgcn_sched_barrier(0);
                float c0 = bv, c1 = 0.f, c2 = 0.f, c3 = 0.f;
                float c4 = 0.f, c5 = 0.f, c6 = 0.f, c7 = 0.f;
                DOTS32(c, tz, wpx);
                zring[sbase + i][lane] = RED8(c);
                GLOAD(xq[i], ppx);                          // x[s+8] (clamped)
                ppx = (ppx < plastx) ? (ppx + STRIDE) : plastx;
            }
            asm volatile("s_waitcnt lgkmcnt(0)" ::: "memory");
            if (lane == 0) *pfv = 8 * j + 8;               // publish batch j
        }
    } else {
        // ================= CONSUMER: the serial chain =================
        f32x4 w[16];
        {
            const float* wb = W + (size_t)(hh * DIM + lane) * (2 * DIM);
#pragma unroll
            for (int i = 0; i < 16; ++i)
                asm volatile("global_load_dwordx4 %0, %1, off offset:%2"
                             : "=v"(w[i]) : "v"(wb), "i"(16 * i));
        }
        asm volatile("s_waitcnt vmcnt(0)" ::: "memory");
        __builtin_amdgcn_sched_barrier(0);
        int wp[32];
#pragma unroll
        for (int j = 0; j < 16; ++j) {
            wp[2 * j]     = pkrtz(w[j].x, w[j].y);
            wp[2 * j + 1] = pkrtz(w[j].z, w[j].w);
        }

        float*       op = out + (size_t)bb * D_SZ + hh * DIM + lane;
        const float* px = sp;
        float xb[8];
#pragma unroll
        for (int i = 0; i < 8; ++i) { GLOAD(xb[i], px); px += STRIDE; }

        float zA[8], zB[8];
        float g = 0.0f;                   // ctx_0 = 0
        __builtin_amdgcn_s_setprio(1);    // favor the serial wave

#define ZPREF(zb, base)                                                       \
        _Pragma("unroll")                                                     \
        for (int i_ = 0; i_ < 8; ++i_) zb[i_] = zring[(base) + i_][lane]

#define RELEASE(val) do { if (lane == 0) *cfv = (val); } while (0)

#define CSTEP(i, zb, N)                                                       \
        do {                                                                  \
            asm volatile("s_waitcnt vmcnt(" #N ")");                          \
            __builtin_amdgcn_sched_barrier(0);                                \
            PACK_PAIR(gp_, g);                                                \
            int tg[32];                                                       \
            RLA32(tg, gp_);                                                   \
            __builtin_amdgcn_sched_barrier(0);                                \
            float a0 = zb[i], a1 = 0.f, a2 = 0.f, a3 = 0.f;                   \
            float a4 = 0.f, a5 = 0.f, a6 = 0.f, a7 = 0.f;                     \
            DOTS32(a, tg, wp);                                                \
            const float y = RED8(a);                                          \
            g = gelu_fast(y);                                                 \
            const float r_ = xb[i] + g;                                       \
            GSTORE(r_, op); op += STRIDE;                                     \
        } while (0)

#define CSTEPL(i, zb, N)                                                      \
        do { CSTEP(i, zb, N); GLOAD(xb[i], px); px += STRIDE; } while (0)

        // startup: batch0 + batch1 prefetched before first step
        SPIN_GE(pfv, 8);
        ZPREF(zA, 0);
        SPIN_GE(pfv, 16);
        ZPREF(zB, 8);
        RELEASE(0);
        // batch 0 (fill vmcnt: slot-i load trailed by (7-i) prologue + 2i step ops)
        CSTEPL(0, zA, 7);  CSTEPL(1, zA, 8);  CSTEPL(2, zA, 9);  CSTEPL(3, zA, 10);
        CSTEPL(4, zA, 11); CSTEPL(5, zA, 12); CSTEPL(6, zA, 13); CSTEPL(7, zA, 14);

        // batches 1..254
        for (int t = 0; t < 127; ++t) {
            const int k1 = 2 * t + 1;
            SPIN_GE(pfv, 8 * k1 + 16);               // batch k1+1 ready
            ZPREF(zA, (8 * k1 + 8) & 63);            // prefetch batch k1+1
            RELEASE(8 * k1);
            CSTEPL(0, zB, 14); CSTEPL(1, zB, 14); CSTEPL(2, zB, 14); CSTEPL(3, zB, 14);
            CSTEPL(4, zB, 14); CSTEPL(5, zB, 14); CSTEPL(6, zB, 14); CSTEPL(7, zB, 14);
            const int k2 = 2 * t + 2;
            SPIN_GE(pfv, 8 * k2 + 16);
            ZPREF(zB, (8 * k2 + 8) & 63);
            RELEASE(8 * k2);
            CSTEPL(0, zA, 14); CSTEPL(1, zA, 14); CSTEPL(2, zA, 14); CSTEPL(3, zA, 14);
            CSTEPL(4, zA, 14); CSTEPL(5, zA, 14); CSTEPL(6, zA, 14); CSTEPL(7, zA, 14);
        }
        // batch 255 (consume zB, no new loads; drain N = 14 - i)
        CSTEP(0, zB, 14); CSTEP(1, zB, 13); CSTEP(2, zB, 12); CSTEP(3, zB, 11);
        CSTEP(4, zB, 10); CSTEP(5, zB, 9);  CSTEP(6, zB, 8);  CSTEP(7, zB, 7);

#undef CSTEPL
#undef CSTEP
#undef RELEASE
#undef ZPREF
    }
}

extern "C" void kernel_launch(void* const* d_in, const int* in_sizes, int n_in,
                              void* d_out, int out_size, void* d_ws, size_t ws_size,
                              hipStream_t stream) {
    const float* src = (const float*)d_in[0];
    const float* W   = (const float*)d_in[1];
    const float* b   = (const float*)d_in[2];
    float* out       = (float*)d_out;

    hipLaunchKernelGGL(bracket_pc, dim3(B_SZ * 8), dim3(128), 0, stream,
                       src, W, b, out);
}

// Round 22
// 536.829 us; speedup vs baseline: 1.3960x; 1.3960x over previous
//
#include <hip/hip_runtime.h>
#include <math.h>

// BracketNet: ctx_{s+1} = GELU(Wc·ctx_s + (b + Wx·x_s)); out_s = x_s + ctx_{s+1}
// pass1: z = b + Wx·x, parallel (issue-bound at 8 waves/SIMD): x packed to
//        f16 pairs (DPP+pkrtz, even lanes), 1 LDS dword write, 8 uniform
//        ds_read_b128, 32 v_dot2_f32_f16. ~50 insts/step. (~130 us)
// pass2: serial chain (r16 engine, 478 cyc/step — best measured): 32-RL
//        batch + one fence + 32 dot2, depth-8 counted-vmcnt volatile-asm
//        global pipeline, 3-term erf gelu. (~408 us)
//
// REVERT of r21 (octet-pipelined RL/dot): perf delta was null (536 vs 538)
// and it introduced a post-timing replay divergence (hazard-window
// perturbation from the extra sched_barrier regions). This file is the r18
// best-passing build, verbatim.
//
// Serial-path scoreboard (cyc/step, measured): readlane+dot2 478 <
// readlane+fma 535 < bpermute+MFMA 1078 < LDS roundtrip ~1100 (r9/r17).
// Step-latency constant is schedule-independent (r11/r13/r16/r21 probes all
// -30..0 cyc). Parallel structures all additive-or-worse: chain-pair (r15),
// fused-z (r19), producer/consumer (r20), octet overlap (r21).

typedef float    f32x4 __attribute__((ext_vector_type(4)));
typedef int      i32x4 __attribute__((ext_vector_type(4)));
typedef _Float16 f16x2 __attribute__((ext_vector_type(2)));

#define S_LEN 2048
#define B_SZ  64
#define D_SZ  512
#define DIM   64
#define STRIDE ((size_t)(B_SZ * D_SZ))   // floats between consecutive s

__device__ __forceinline__ int pkrtz(float a, float b) {
    return __builtin_bit_cast(int, __builtin_amdgcn_cvt_pkrtz(a, b));
}

__device__ __forceinline__ float fdot2h(int pack, int wpk, float acc) {
#if __has_builtin(__builtin_amdgcn_fdot2)
    return __builtin_amdgcn_fdot2(__builtin_bit_cast(f16x2, pack),
                                  __builtin_bit_cast(f16x2, wpk), acc, false);
#else
    float d;
    asm("v_dot2_f32_f16 %0, %1, %2, %3"
        : "=v"(d)
        : "v"(__builtin_bit_cast(f16x2, pack)),
          "v"(__builtin_bit_cast(f16x2, wpk)), "v"(acc));
    return d;
#endif
}

// 3-term A&S 7.1.25 erf gelu (|eps|<=2.5e-5), fma-combined tail.
__device__ __forceinline__ float gelu_fast(float y) {
    const float ax = fabsf(y) * 0.70710678118654752440f;
    const float t  = __builtin_amdgcn_rcpf(fmaf(0.47047f, ax, 1.0f));
    const float e  = __builtin_amdgcn_exp2f(-ax * ax * 1.44269504088896f);
    float p = fmaf(0.7478556f, t, -0.0958798f);
    p = fmaf(p, t, 0.3480242f);
    p *= t;
    float er = fmaf(-p, e, 1.0f);
    er = copysignf(er, y);
    const float m = 0.5f * y;
    return fmaf(m, er, m);
}

// ---------------- Pass 1: z = b + Wx·x, one wave per (b,h,128-s chunk).
// Packed-f16 LDS broadcast + dot2 (issue-bound; LDS latency hidden by TLP).
__global__ __launch_bounds__(64, 1) void bracket_pass1(
    const float* __restrict__ src, const float* __restrict__ W,
    const float* __restrict__ bias, float* __restrict__ zout)
{
    const int lane = threadIdx.x;
    const int ck   = blockIdx.x >> 9;          // 0..15 (128 s each)
    const int bb   = (blockIdx.x >> 3) & 63;
    const int hh   = blockIdx.x & 7;

    // Wx row fp32 (pinned), packed to f16 pairs: wp[p] = (Wx[d][2p], Wx[d][2p+1]).
    f32x4 w[16];
    {
        const float* wb = W + (size_t)(hh * DIM + lane) * (2 * DIM) + DIM;
#pragma unroll
        for (int i = 0; i < 16; ++i)
            asm volatile("global_load_dwordx4 %0, %1, off offset:%2"
                         : "=v"(w[i]) : "v"(wb), "i"(16 * i));
    }
    asm volatile("s_waitcnt vmcnt(0)" ::: "memory");
    __builtin_amdgcn_sched_barrier(0);

    int wp[32];
#pragma unroll
    for (int j = 0; j < 16; ++j) {
        wp[2 * j]     = pkrtz(w[j].x, w[j].y);
        wp[2 * j + 1] = pkrtz(w[j].z, w[j].w);
    }

    const float bv = bias[hh * DIM + lane];

    // Slots 0..31 = packed pairs; 32..63 = dummy sink for odd lanes
    // (even lane 2k -> slot k; per-bank 2-way access = free).
    __shared__ __align__(16) int xpk[2][2 * DIM];
    const int wslot = (lane >> 1) | ((lane & 1) << 5);

    const float* sp = src  + (size_t)(ck * 128) * STRIDE + (size_t)bb * D_SZ + hh * DIM + lane;
    float*       zp = zout + (size_t)(ck * 128) * STRIDE + (size_t)bb * D_SZ + hh * DIM + lane;

    float x0 = sp[0], x1 = sp[STRIDE];
    const float* pp    = sp + 2 * STRIDE;
    const float* plast = sp + 127 * STRIDE;

#define P1STEP(cur, xc)                                                       \
    do {                                                                      \
        const int xi  = __float_as_int(xc);                                   \
        const int xsh = __builtin_amdgcn_mov_dpp(xi, 0x101, 0xf, 0xf, true);  \
        xpk[cur][wslot] = pkrtz(xc, __int_as_float(xsh));                     \
        const float xn = *pp;                                                 \
        pp = (pp < plast) ? (pp + STRIDE) : plast;                            \
        const i32x4* vv = (const i32x4*)xpk[cur];                             \
        float a0 = bv, a1 = 0.f, a2 = 0.f, a3 = 0.f;                          \
        float a4 = 0.f, a5 = 0.f, a6 = 0.f, a7 = 0.f;                         \
        _Pragma("unroll")                                                     \
        for (int j = 0; j < 8; j += 2) {                                      \
            const i32x4 u0 = vv[j], u1 = vv[j + 1];                           \
            a0 = fdot2h(u0.x, wp[4 * j + 0], a0);                             \
            a1 = fdot2h(u0.y, wp[4 * j + 1], a1);                             \
            a2 = fdot2h(u0.z, wp[4 * j + 2], a2);                             \
            a3 = fdot2h(u0.w, wp[4 * j + 3], a3);                             \
            a4 = fdot2h(u1.x, wp[4 * j + 4], a4);                             \
            a5 = fdot2h(u1.y, wp[4 * j + 5], a5);                             \
            a6 = fdot2h(u1.z, wp[4 * j + 6], a6);                             \
            a7 = fdot2h(u1.w, wp[4 * j + 7], a7);                             \
        }                                                                     \
        *zp = ((a0 + a1) + (a2 + a3)) + ((a4 + a5) + (a6 + a7));              \
        zp += STRIDE;                                                         \
        xc = xn;                                                              \
    } while (0)

    for (int i = 0; i < 128; i += 2) {
        P1STEP(0, x0);
        P1STEP(1, x1);
    }
#undef P1STEP
}

// ---------------- Pass 2 (r16 engine, verbatim): serial chain, single 32-RL
// batch dot2 GEMV, depth-8 counted-vmcnt volatile-asm prefetch.
#define GLOAD(dst, ptr) \
    asm volatile("global_load_dword %0, %1, off" : "=v"(dst) : "v"(ptr))
#define GSTORE(val, ptr) \
    asm volatile("global_store_dword %1, %0, off" : : "v"(val), "v"(ptr) : "memory")

#define DOT32()                                                               \
    do {                                                                      \
        const int t0  = __builtin_amdgcn_readlane(gpi, 0);                    \
        const int t1  = __builtin_amdgcn_readlane(gpi, 2);                    \
        const int t2  = __builtin_amdgcn_readlane(gpi, 4);                    \
        const int t3  = __builtin_amdgcn_readlane(gpi, 6);                    \
        const int t4  = __builtin_amdgcn_readlane(gpi, 8);                    \
        const int t5  = __builtin_amdgcn_readlane(gpi, 10);                   \
        const int t6  = __builtin_amdgcn_readlane(gpi, 12);                   \
        const int t7  = __builtin_amdgcn_readlane(gpi, 14);                   \
        const int t8  = __builtin_amdgcn_readlane(gpi, 16);                   \
        const int t9  = __builtin_amdgcn_readlane(gpi, 18);                   \
        const int t10 = __builtin_amdgcn_readlane(gpi, 20);                   \
        const int t11 = __builtin_amdgcn_readlane(gpi, 22);                   \
        const int t12 = __builtin_amdgcn_readlane(gpi, 24);                   \
        const int t13 = __builtin_amdgcn_readlane(gpi, 26);                   \
        const int t14 = __builtin_amdgcn_readlane(gpi, 28);                   \
        const int t15 = __builtin_amdgcn_readlane(gpi, 30);                   \
        const int t16 = __builtin_amdgcn_readlane(gpi, 32);                   \
        const int t17 = __builtin_amdgcn_readlane(gpi, 34);                   \
        const int t18 = __builtin_amdgcn_readlane(gpi, 36);                   \
        const int t19 = __builtin_amdgcn_readlane(gpi, 38);                   \
        const int t20 = __builtin_amdgcn_readlane(gpi, 40);                   \
        const int t21 = __builtin_amdgcn_readlane(gpi, 42);                   \
        const int t22 = __builtin_amdgcn_readlane(gpi, 44);                   \
        const int t23 = __builtin_amdgcn_readlane(gpi, 46);                   \
        const int t24 = __builtin_amdgcn_readlane(gpi, 48);                   \
        const int t25 = __builtin_amdgcn_readlane(gpi, 50);                   \
        const int t26 = __builtin_amdgcn_readlane(gpi, 52);                   \
        const int t27 = __builtin_amdgcn_readlane(gpi, 54);                   \
        const int t28 = __builtin_amdgcn_readlane(gpi, 56);                   \
        const int t29 = __builtin_amdgcn_readlane(gpi, 58);                   \
        const int t30 = __builtin_amdgcn_readlane(gpi, 60);                   \
        const int t31 = __builtin_amdgcn_readlane(gpi, 62);                   \
        __builtin_amdgcn_sched_barrier(0);                                    \
        a0 = fdot2h(t0,  wp[0],  a0);  a1 = fdot2h(t1,  wp[1],  a1);          \
        a2 = fdot2h(t2,  wp[2],  a2);  a3 = fdot2h(t3,  wp[3],  a3);          \
        a4 = fdot2h(t4,  wp[4],  a4);  a5 = fdot2h(t5,  wp[5],  a5);          \
        a6 = fdot2h(t6,  wp[6],  a6);  a7 = fdot2h(t7,  wp[7],  a7);          \
        a0 = fdot2h(t8,  wp[8],  a0);  a1 = fdot2h(t9,  wp[9],  a1);          \
        a2 = fdot2h(t10, wp[10], a2);  a3 = fdot2h(t11, wp[11], a3);          \
        a4 = fdot2h(t12, wp[12], a4);  a5 = fdot2h(t13, wp[13], a5);          \
        a6 = fdot2h(t14, wp[14], a6);  a7 = fdot2h(t15, wp[15], a7);          \
        a0 = fdot2h(t16, wp[16], a0);  a1 = fdot2h(t17, wp[17], a1);          \
        a2 = fdot2h(t18, wp[18], a2);  a3 = fdot2h(t19, wp[19], a3);          \
        a4 = fdot2h(t20, wp[20], a4);  a5 = fdot2h(t21, wp[21], a5);          \
        a6 = fdot2h(t22, wp[22], a6);  a7 = fdot2h(t23, wp[23], a7);          \
        a0 = fdot2h(t24, wp[24], a0);  a1 = fdot2h(t25, wp[25], a1);          \
        a2 = fdot2h(t26, wp[26], a2);  a3 = fdot2h(t27, wp[27], a3);          \
        a4 = fdot2h(t28, wp[28], a4);  a5 = fdot2h(t29, wp[29], a5);          \
        a6 = fdot2h(t30, wp[30], a6);  a7 = fdot2h(t31, wp[31], a7);          \
    } while (0)

__global__ __launch_bounds__(64, 1) void bracket_pass2(
    const float* __restrict__ src, const float* __restrict__ W,
    float* __restrict__ out)   // out holds z on entry; overwritten with result
{
    const int lane = threadIdx.x;
    const int bb   = blockIdx.x >> 3;
    const int hh   = blockIdx.x & 7;

    f32x4 w[16];
    {
        const float* wb = W + (size_t)(hh * DIM + lane) * (2 * DIM);
#pragma unroll
        for (int i = 0; i < 16; ++i)
            asm volatile("global_load_dwordx4 %0, %1, off offset:%2"
                         : "=v"(w[i]) : "v"(wb), "i"(16 * i));
    }
    asm volatile("s_waitcnt vmcnt(0)" ::: "memory");
    __builtin_amdgcn_sched_barrier(0);

    int wp[32];
#pragma unroll
    for (int j = 0; j < 16; ++j) {
        wp[2 * j]     = pkrtz(w[j].x, w[j].y);
        wp[2 * j + 1] = pkrtz(w[j].z, w[j].w);
    }

    const float* sp = src + (size_t)bb * D_SZ + hh * DIM + lane;
    float*       op = out + (size_t)bb * D_SZ + hh * DIM + lane;  // store ptr
    const float* px = sp;                                         // x load ptr
    const float* pz = op;                                         // z load ptr

    float xb[8], zb[8];
    float g = 0.0f;   // ctx_0 = 0

#pragma unroll
    for (int i = 0; i < 8; ++i) {
        GLOAD(xb[i], px); px += STRIDE;
        GLOAD(zb[i], pz); pz += STRIDE;
    }

#define STEP_CORE(i)                                                          \
    do {                                                                      \
        const float zi = zb[i];                                               \
        const int gi  = __float_as_int(g);                                    \
        const int gsh = __builtin_amdgcn_mov_dpp(gi, 0x101, 0xf, 0xf, true);  \
        const int gpi = pkrtz(g, __int_as_float(gsh));                        \
        float a0 = zi, a1 = 0.f, a2 = 0.f, a3 = 0.f;                          \
        float a4 = 0.f, a5 = 0.f, a6 = 0.f, a7 = 0.f;                         \
        DOT32();                                                              \
        const float y = ((a0 + a1) + (a2 + a3)) + ((a4 + a5) + (a6 + a7));    \
        g = gelu_fast(y);                                                     \
        const float r = xb[i] + g;                                            \
        GSTORE(r, op);                                                        \
        op += STRIDE;                                                         \
    } while (0)

#define STEPL(i, N)                                                           \
    do {                                                                      \
        asm volatile("s_waitcnt vmcnt(" #N ")");                              \
        __builtin_amdgcn_sched_barrier(0);                                    \
        STEP_CORE(i);                                                         \
        GLOAD(xb[i], px); px += STRIDE;                                       \
        GLOAD(zb[i], pz); pz += STRIDE;                                       \
    } while (0)

#define STEPE(i, N)                                                           \
    do {                                                                      \
        asm volatile("s_waitcnt vmcnt(" #N ")");                              \
        __builtin_amdgcn_sched_barrier(0);                                    \
        STEP_CORE(i);                                                         \
    } while (0)

    STEPL(0, 14); STEPL(1, 15); STEPL(2, 16); STEPL(3, 17);
    STEPL(4, 18); STEPL(5, 19); STEPL(6, 20); STEPL(7, 21);
    for (int blk = 0; blk < 254; ++blk) {
        STEPL(0, 21); STEPL(1, 21); STEPL(2, 21); STEPL(3, 21);
        STEPL(4, 21); STEPL(5, 21); STEPL(6, 21); STEPL(7, 21);
    }
    STEPE(0, 21); STEPE(1, 19); STEPE(2, 17); STEPE(3, 15);
    STEPE(4, 13); STEPE(5, 11); STEPE(6, 9);  STEPE(7, 7);

#undef STEPL
#undef STEPE
#undef STEP_CORE
}

extern "C" void kernel_launch(void* const* d_in, const int* in_sizes, int n_in,
                              void* d_out, int out_size, void* d_ws, size_t ws_size,
                              hipStream_t stream) {
    const float* src = (const float*)d_in[0];
    const float* W   = (const float*)d_in[1];
    const float* b   = (const float*)d_in[2];
    float* out       = (float*)d_out;

    hipLaunchKernelGGL(bracket_pass1, dim3(B_SZ * 8 * 16), dim3(64), 0, stream,
                       src, W, b, out);
    hipLaunchKernelGGL(bracket_pass2, dim3(B_SZ * 8), dim3(64), 0, stream,
                       src, W, out);
}

// Round 24
// 536.795 us; speedup vs baseline: 1.3961x; 1.0001x over previous
//
#include <hip/hip_runtime.h>
#include <math.h>

// BracketNet: ctx_{s+1} = GELU(Wc·ctx_s + (b + Wx·x_s)); out_s = x_s + ctx_{s+1}
// FINAL (r22 build, best passing: 536.8 us).
// pass1: z = b + Wx·x, parallel (issue-bound at 8 waves/SIMD): x packed to
//        f16 pairs (DPP+pkrtz, even lanes), 1 LDS dword write, 8 uniform
//        ds_read_b128, 32 v_dot2_f32_f16. ~50 insts/step. (~130 us)
// pass2: serial chain (r16 engine, 478 cyc/step — best measured): 32-RL
//        batch + one fence + 32 dot2, depth-8 counted-vmcnt volatile-asm
//        global pipeline, 3-term erf gelu. (~408 us)
//
// Why this is the floor (session evidence):
// - Serial-path engine scoreboard (cyc/step): readlane+dot2 478 <
//   readlane+fma 535 < bpermute+MFMA 1078 < LDS roundtrip ~1100.
// - Step latency is schedule-independent: halve RLs (-30), halve MACs (-30),
//   single-fence (-57), octet overlap (-1).
// - Parallel structures additive-or-worse on one wave: chain-pair (r15 996),
//   fused-z (r19 672), octet (r21 null+replay-divergence).
// - Cross-wave offload: 1 producer is producer-paced (r20 749); 3 producers
//   deadlocked/crashed (r23). Protocol complexity exceeds the ~130us upside.
// Wall = 2048 x 478 cyc serial recurrence + issue-bound pass1; neither is a
// counter-visible HBM/VALU roofline — it is the structural latency floor of
// a strict nonlinear scan with 64-wide state at 1 wave/SIMD.

typedef float    f32x4 __attribute__((ext_vector_type(4)));
typedef int      i32x4 __attribute__((ext_vector_type(4)));
typedef _Float16 f16x2 __attribute__((ext_vector_type(2)));

#define S_LEN 2048
#define B_SZ  64
#define D_SZ  512
#define DIM   64
#define STRIDE ((size_t)(B_SZ * D_SZ))   // floats between consecutive s

__device__ __forceinline__ int pkrtz(float a, float b) {
    return __builtin_bit_cast(int, __builtin_amdgcn_cvt_pkrtz(a, b));
}

__device__ __forceinline__ float fdot2h(int pack, int wpk, float acc) {
#if __has_builtin(__builtin_amdgcn_fdot2)
    return __builtin_amdgcn_fdot2(__builtin_bit_cast(f16x2, pack),
                                  __builtin_bit_cast(f16x2, wpk), acc, false);
#else
    float d;
    asm("v_dot2_f32_f16 %0, %1, %2, %3"
        : "=v"(d)
        : "v"(__builtin_bit_cast(f16x2, pack)),
          "v"(__builtin_bit_cast(f16x2, wpk)), "v"(acc));
    return d;
#endif
}

// 3-term A&S 7.1.25 erf gelu (|eps|<=2.5e-5), fma-combined tail.
__device__ __forceinline__ float gelu_fast(float y) {
    const float ax = fabsf(y) * 0.70710678118654752440f;
    const float t  = __builtin_amdgcn_rcpf(fmaf(0.47047f, ax, 1.0f));
    const float e  = __builtin_amdgcn_exp2f(-ax * ax * 1.44269504088896f);
    float p = fmaf(0.7478556f, t, -0.0958798f);
    p = fmaf(p, t, 0.3480242f);
    p *= t;
    float er = fmaf(-p, e, 1.0f);
    er = copysignf(er, y);
    const float m = 0.5f * y;
    return fmaf(m, er, m);
}

// ---------------- Pass 1: z = b + Wx·x, one wave per (b,h,128-s chunk).
// Packed-f16 LDS broadcast + dot2 (issue-bound; LDS latency hidden by TLP).
__global__ __launch_bounds__(64, 1) void bracket_pass1(
    const float* __restrict__ src, const float* __restrict__ W,
    const float* __restrict__ bias, float* __restrict__ zout)
{
    const int lane = threadIdx.x;
    const int ck   = blockIdx.x >> 9;          // 0..15 (128 s each)
    const int bb   = (blockIdx.x >> 3) & 63;
    const int hh   = blockIdx.x & 7;

    // Wx row fp32 (pinned), packed to f16 pairs: wp[p] = (Wx[d][2p], Wx[d][2p+1]).
    f32x4 w[16];
    {
        const float* wb = W + (size_t)(hh * DIM + lane) * (2 * DIM) + DIM;
#pragma unroll
        for (int i = 0; i < 16; ++i)
            asm volatile("global_load_dwordx4 %0, %1, off offset:%2"
                         : "=v"(w[i]) : "v"(wb), "i"(16 * i));
    }
    asm volatile("s_waitcnt vmcnt(0)" ::: "memory");
    __builtin_amdgcn_sched_barrier(0);

    int wp[32];
#pragma unroll
    for (int j = 0; j < 16; ++j) {
        wp[2 * j]     = pkrtz(w[j].x, w[j].y);
        wp[2 * j + 1] = pkrtz(w[j].z, w[j].w);
    }

    const float bv = bias[hh * DIM + lane];

    // Slots 0..31 = packed pairs; 32..63 = dummy sink for odd lanes
    // (even lane 2k -> slot k; per-bank 2-way access = free).
    __shared__ __align__(16) int xpk[2][2 * DIM];
    const int wslot = (lane >> 1) | ((lane & 1) << 5);

    const float* sp = src  + (size_t)(ck * 128) * STRIDE + (size_t)bb * D_SZ + hh * DIM + lane;
    float*       zp = zout + (size_t)(ck * 128) * STRIDE + (size_t)bb * D_SZ + hh * DIM + lane;

    float x0 = sp[0], x1 = sp[STRIDE];
    const float* pp    = sp + 2 * STRIDE;
    const float* plast = sp + 127 * STRIDE;

#define P1STEP(cur, xc)                                                       \
    do {                                                                      \
        const int xi  = __float_as_int(xc);                                   \
        const int xsh = __builtin_amdgcn_mov_dpp(xi, 0x101, 0xf, 0xf, true);  \
        xpk[cur][wslot] = pkrtz(xc, __int_as_float(xsh));                     \
        const float xn = *pp;                                                 \
        pp = (pp < plast) ? (pp + STRIDE) : plast;                            \
        const i32x4* vv = (const i32x4*)xpk[cur];                             \
        float a0 = bv, a1 = 0.f, a2 = 0.f, a3 = 0.f;                          \
        float a4 = 0.f, a5 = 0.f, a6 = 0.f, a7 = 0.f;                         \
        _Pragma("unroll")                                                     \
        for (int j = 0; j < 8; j += 2) {                                      \
            const i32x4 u0 = vv[j], u1 = vv[j + 1];                           \
            a0 = fdot2h(u0.x, wp[4 * j + 0], a0);                             \
            a1 = fdot2h(u0.y, wp[4 * j + 1], a1);                             \
            a2 = fdot2h(u0.z, wp[4 * j + 2], a2);                             \
            a3 = fdot2h(u0.w, wp[4 * j + 3], a3);                             \
            a4 = fdot2h(u1.x, wp[4 * j + 4], a4);                             \
            a5 = fdot2h(u1.y, wp[4 * j + 5], a5);                             \
            a6 = fdot2h(u1.z, wp[4 * j + 6], a6);                             \
            a7 = fdot2h(u1.w, wp[4 * j + 7], a7);                             \
        }                                                                     \
        *zp = ((a0 + a1) + (a2 + a3)) + ((a4 + a5) + (a6 + a7));              \
        zp += STRIDE;                                                         \
        xc = xn;                                                              \
    } while (0)

    for (int i = 0; i < 128; i += 2) {
        P1STEP(0, x0);
        P1STEP(1, x1);
    }
#undef P1STEP
}

// ---------------- Pass 2 (r16 engine, verbatim): serial chain, single 32-RL
// batch dot2 GEMV, depth-8 counted-vmcnt volatile-asm prefetch.
#define GLOAD(dst, ptr) \
    asm volatile("global_load_dword %0, %1, off" : "=v"(dst) : "v"(ptr))
#define GSTORE(val, ptr) \
    asm volatile("global_store_dword %1, %0, off" : : "v"(val), "v"(ptr) : "memory")

#define DOT32()                                                               \
    do {                                                                      \
        const int t0  = __builtin_amdgcn_readlane(gpi, 0);                    \
        const int t1  = __builtin_amdgcn_readlane(gpi, 2);                    \
        const int t2  = __builtin_amdgcn_readlane(gpi, 4);                    \
        const int t3  = __builtin_amdgcn_readlane(gpi, 6);                    \
        const int t4  = __builtin_amdgcn_readlane(gpi, 8);                    \
        const int t5  = __builtin_amdgcn_readlane(gpi, 10);                   \
        const int t6  = __builtin_amdgcn_readlane(gpi, 12);                   \
        const int t7  = __builtin_amdgcn_readlane(gpi, 14);                   \
        const int t8  = __builtin_amdgcn_readlane(gpi, 16);                   \
        const int t9  = __builtin_amdgcn_readlane(gpi, 18);                   \
        const int t10 = __builtin_amdgcn_readlane(gpi, 20);                   \
        const int t11 = __builtin_amdgcn_readlane(gpi, 22);                   \
        const int t12 = __builtin_amdgcn_readlane(gpi, 24);                   \
        const int t13 = __builtin_amdgcn_readlane(gpi, 26);                   \
        const int t14 = __builtin_amdgcn_readlane(gpi, 28);                   \
        const int t15 = __builtin_amdgcn_readlane(gpi, 30);                   \
        const int t16 = __builtin_amdgcn_readlane(gpi, 32);                   \
        const int t17 = __builtin_amdgcn_readlane(gpi, 34);                   \
        const int t18 = __builtin_amdgcn_readlane(gpi, 36);                   \
        const int t19 = __builtin_amdgcn_readlane(gpi, 38);                   \
        const int t20 = __builtin_amdgcn_readlane(gpi, 40);                   \
        const int t21 = __builtin_amdgcn_readlane(gpi, 42);                   \
        const int t22 = __builtin_amdgcn_readlane(gpi, 44);                   \
        const int t23 = __builtin_amdgcn_readlane(gpi, 46);                   \
        const int t24 = __builtin_amdgcn_readlane(gpi, 48);                   \
        const int t25 = __builtin_amdgcn_readlane(gpi, 50);                   \
        const int t26 = __builtin_amdgcn_readlane(gpi, 52);                   \
        const int t27 = __builtin_amdgcn_readlane(gpi, 54);                   \
        const int t28 = __builtin_amdgcn_readlane(gpi, 56);                   \
        const int t29 = __builtin_amdgcn_readlane(gpi, 58);                   \
        const int t30 = __builtin_amdgcn_readlane(gpi, 60);                   \
        const int t31 = __builtin_amdgcn_readlane(gpi, 62);                   \
        __builtin_amdgcn_sched_barrier(0);                                    \
        a0 = fdot2h(t0,  wp[0],  a0);  a1 = fdot2h(t1,  wp[1],  a1);          \
        a2 = fdot2h(t2,  wp[2],  a2);  a3 = fdot2h(t3,  wp[3],  a3);          \
        a4 = fdot2h(t4,  wp[4],  a4);  a5 = fdot2h(t5,  wp[5],  a5);          \
        a6 = fdot2h(t6,  wp[6],  a6);  a7 = fdot2h(t7,  wp[7],  a7);          \
        a0 = fdot2h(t8,  wp[8],  a0);  a1 = fdot2h(t9,  wp[9],  a1);          \
        a2 = fdot2h(t10, wp[10], a2);  a3 = fdot2h(t11, wp[11], a3);          \
        a4 = fdot2h(t12, wp[12], a4);  a5 = fdot2h(t13, wp[13], a5);          \
        a6 = fdot2h(t14, wp[14], a6);  a7 = fdot2h(t15, wp[15], a7);          \
        a0 = fdot2h(t16, wp[16], a0);  a1 = fdot2h(t17, wp[17], a1);          \
        a2 = fdot2h(t18, wp[18], a2);  a3 = fdot2h(t19, wp[19], a3);          \
        a4 = fdot2h(t20, wp[20], a4);  a5 = fdot2h(t21, wp[21], a5);          \
        a6 = fdot2h(t22, wp[22], a6);  a7 = fdot2h(t23, wp[23], a7);          \
        a0 = fdot2h(t24, wp[24], a0);  a1 = fdot2h(t25, wp[25], a1);          \
        a2 = fdot2h(t26, wp[26], a2);  a3 = fdot2h(t27, wp[27], a3);          \
        a4 = fdot2h(t28, wp[28], a4);  a5 = fdot2h(t29, wp[29], a5);          \
        a6 = fdot2h(t30, wp[30], a6);  a7 = fdot2h(t31, wp[31], a7);          \
    } while (0)

__global__ __launch_bounds__(64, 1) void bracket_pass2(
    const float* __restrict__ src, const float* __restrict__ W,
    float* __restrict__ out)   // out holds z on entry; overwritten with result
{
    const int lane = threadIdx.x;
    const int bb   = blockIdx.x >> 3;
    const int hh   = blockIdx.x & 7;

    f32x4 w[16];
    {
        const float* wb = W + (size_t)(hh * DIM + lane) * (2 * DIM);
#pragma unroll
        for (int i = 0; i < 16; ++i)
            asm volatile("global_load_dwordx4 %0, %1, off offset:%2"
                         : "=v"(w[i]) : "v"(wb), "i"(16 * i));
    }
    asm volatile("s_waitcnt vmcnt(0)" ::: "memory");
    __builtin_amdgcn_sched_barrier(0);

    int wp[32];
#pragma unroll
    for (int j = 0; j < 16; ++j) {
        wp[2 * j]     = pkrtz(w[j].x, w[j].y);
        wp[2 * j + 1] = pkrtz(w[j].z, w[j].w);
    }

    const float* sp = src + (size_t)bb * D_SZ + hh * DIM + lane;
    float*       op = out + (size_t)bb * D_SZ + hh * DIM + lane;  // store ptr
    const float* px = sp;                                         // x load ptr
    const float* pz = op;                                         // z load ptr

    float xb[8], zb[8];
    float g = 0.0f;   // ctx_0 = 0

#pragma unroll
    for (int i = 0; i < 8; ++i) {
        GLOAD(xb[i], px); px += STRIDE;
        GLOAD(zb[i], pz); pz += STRIDE;
    }

#define STEP_CORE(i)                                                          \
    do {                                                                      \
        const float zi = zb[i];                                               \
        const int gi  = __float_as_int(g);                                    \
        const int gsh = __builtin_amdgcn_mov_dpp(gi, 0x101, 0xf, 0xf, true);  \
        const int gpi = pkrtz(g, __int_as_float(gsh));                        \
        float a0 = zi, a1 = 0.f, a2 = 0.f, a3 = 0.f;                          \
        float a4 = 0.f, a5 = 0.f, a6 = 0.f, a7 = 0.f;                         \
        DOT32();                                                              \
        const float y = ((a0 + a1) + (a2 + a3)) + ((a4 + a5) + (a6 + a7));    \
        g = gelu_fast(y);                                                     \
        const float r = xb[i] + g;                                            \
        GSTORE(r, op);                                                        \
        op += STRIDE;                                                         \
    } while (0)

#define STEPL(i, N)                                                           \
    do {                                                                      \
        asm volatile("s_waitcnt vmcnt(" #N ")");                              \
        __builtin_amdgcn_sched_barrier(0);                                    \
        STEP_CORE(i);                                                         \
        GLOAD(xb[i], px); px += STRIDE;                                       \
        GLOAD(zb[i], pz); pz += STRIDE;                                       \
    } while (0)

#define STEPE(i, N)                                                           \
    do {                                                                      \
        asm volatile("s_waitcnt vmcnt(" #N ")");                              \
        __builtin_amdgcn_sched_barrier(0);                                    \
        STEP_CORE(i);                                                         \
    } while (0)

    STEPL(0, 14); STEPL(1, 15); STEPL(2, 16); STEPL(3, 17);
    STEPL(4, 18); STEPL(5, 19); STEPL(6, 20); STEPL(7, 21);
    for (int blk = 0; blk < 254; ++blk) {
        STEPL(0, 21); STEPL(1, 21); STEPL(2, 21); STEPL(3, 21);
        STEPL(4, 21); STEPL(5, 21); STEPL(6, 21); STEPL(7, 21);
    }
    STEPE(0, 21); STEPE(1, 19); STEPE(2, 17); STEPE(3, 15);
    STEPE(4, 13); STEPE(5, 11); STEPE(6, 9);  STEPE(7, 7);

#undef STEPL
#undef STEPE
#undef STEP_CORE
}

extern "C" void kernel_launch(void* const* d_in, const int* in_sizes, int n_in,
                              void* d_out, int out_size, void* d_ws, size_t ws_size,
                              hipStream_t stream) {
    const float* src = (const float*)d_in[0];
    const float* W   = (const float*)d_in[1];
    const float* b   = (const float*)d_in[2];
    float* out       = (float*)d_out;

    hipLaunchKernelGGL(bracket_pass1, dim3(B_SZ * 8 * 16), dim3(64), 0, stream,
                       src, W, b, out);
    hipLaunchKernelGGL(bracket_pass2, dim3(B_SZ * 8), dim3(64), 0, stream,
                       src, W, out);
}